// Round 5
// baseline (862.759 us; speedup 1.0000x reference)
//
#include <hip/hip_runtime.h>
#include <cstdint>
#include <cstddef>

typedef unsigned int  u32;
typedef unsigned short u16;
typedef _Float16 f16;
typedef _Float16 f16x2 __attribute__((ext_vector_type(2)));
typedef _Float16 half8 __attribute__((ext_vector_type(8)));
typedef float    f32x4v __attribute__((ext_vector_type(4)));
typedef int      i32x4 __attribute__((ext_vector_type(4)));

#define BATCH 64
#define TSEQ  512
#define DEMB  300
#define KPAD  320
#define HDIM  256
#define G4    1024
#define NCLS  9

__device__ __forceinline__ u32 packf16(float a, float b) {
  f16x2 v; v.x = (f16)a; v.y = (f16)b;
  return __builtin_bit_cast(u32, v);
}
__device__ __forceinline__ float f16f(u16 x) {
  return (float)__builtin_bit_cast(f16, x);
}
__device__ __forceinline__ float sigm_fast(float x) {
  return __builtin_amdgcn_rcpf(1.f + __expf(-x));
}
__device__ __forceinline__ float tanh_fast(float x) {
  float ax = __builtin_fabsf(x);
  float e = __expf(-2.f * ax);
  float t = (1.f - e) * __builtin_amdgcn_rcpf(1.f + e);
  return copysignf(t, x);
}
__device__ __forceinline__ int sdot4(int a, int b, int c) {
#if __has_builtin(__builtin_amdgcn_sdot4)
  return __builtin_amdgcn_sdot4(a, b, c, false);
#else
  int r;
  asm volatile("v_dot4_i32_i8 %0, %1, %2, %3" : "=v"(r) : "v"(a), "v"(b), "v"(c));
  return r;
#endif
}

// ---------------- P1: embf16[v][320] = f16(emb[v][0..299]), zero-pad 300..319 ----
__global__ __launch_bounds__(256) void embcvt_k(const float* __restrict__ emb,
                                                u16* __restrict__ out) {
  const int v  = blockIdx.x * 16 + (threadIdx.x >> 4);
  const int kc = threadIdx.x & 15;
  u32* __restrict__ dst = (u32*)(out + (size_t)v * KPAD + kc * 20);
  if (kc < 15) {
    const float* __restrict__ src = emb + (size_t)v * DEMB + kc * 20;
    float tmp[20];
#pragma unroll
    for (int j = 0; j < 20; ++j) tmp[j] = src[j];
#pragma unroll
    for (int j = 0; j < 10; ++j) dst[j] = packf16(tmp[2 * j], tmp[2 * j + 1]);
  } else {
#pragma unroll
    for (int j = 0; j < 10; ++j) dst[j] = 0u;
  }
}

// ---------------- P2: wkt[dir][col][320] = f16(Wk[k][col]), zero-pad k>=300 -----
__global__ __launch_bounds__(256) void wkt_k(const float* __restrict__ Wk_f,
                                             const float* __restrict__ Wk_b,
                                             u16* __restrict__ wkt) {
  const int dir = blockIdx.y;
  const float* __restrict__ Wk = dir ? Wk_b : Wk_f;
  const int col = blockIdx.x * 16 + (threadIdx.x >> 4);
  const int kc  = threadIdx.x & 15;
  u32* __restrict__ dst = (u32*)(wkt + ((size_t)dir * G4 + col) * KPAD + kc * 20);
  if (kc < 15) {
    float tmp[20];
#pragma unroll
    for (int j = 0; j < 20; ++j) tmp[j] = Wk[(size_t)(kc * 20 + j) * G4 + col];
#pragma unroll
    for (int j = 0; j < 10; ++j) dst[j] = packf16(tmp[2 * j], tmp[2 * j + 1]);
  } else {
#pragma unroll
    for (int j = 0; j < 10; ++j) dst[j] = 0u;
  }
}

// ---------------- P3: wr8[dir][col][256] = int8(Wr[k][col] * 512), k-major ----
__global__ __launch_bounds__(256) void wr8_k(const float* __restrict__ Wr_f,
                                             const float* __restrict__ Wr_b,
                                             signed char* __restrict__ wr8) {
  const int dir = blockIdx.y;
  const float* __restrict__ Wr = dir ? Wr_b : Wr_f;
  const int col = blockIdx.x * 16 + (threadIdx.x >> 4);
  const int k0  = (threadIdx.x & 15) * 16;
  float tmp[16];
#pragma unroll
  for (int j = 0; j < 16; ++j) tmp[j] = Wr[(size_t)(k0 + j) * G4 + col];
  u32 pw[4];
#pragma unroll
  for (int jj = 0; jj < 4; ++jj) {
    u32 p = 0;
#pragma unroll
    for (int b = 0; b < 4; ++b) {
      int q = (int)__builtin_rintf(tmp[4 * jj + b] * 512.f);
      q = q > 127 ? 127 : (q < -127 ? -127 : q);
      p |= ((u32)(q & 255)) << (8 * b);
    }
    pw[jj] = p;
  }
  *(uint4*)(wr8 + ((size_t)dir * G4 + col) * HDIM + k0) =
      make_uint4(pw[0], pw[1], pw[2], pw[3]);
}

// ---------------- K1: xz = emb[inputs] @ Wk + b  (MFMA f16) ----------------
__global__ __launch_bounds__(256) void xz_gemm_k(
    const int* __restrict__ inputs, const u16* __restrict__ wkt,
    const u16* __restrict__ embf16, const float* __restrict__ b_f,
    const float* __restrict__ b_b, u16* __restrict__ xz)
{
  __shared__ __align__(16) u16 As[128 * 40];   // [m][k], k-major, pad 32->40
  __shared__ __align__(16) u16 Bs[128 * 40];   // [n][k], k-major
  const int tid  = threadIdx.x;
  const int wv   = tid >> 6, lane = tid & 63;
  const int quad = lane >> 4, fl = lane & 15;
  const int cbi  = blockIdx.x;                 // 0..15
  const int dir  = cbi >> 3;
  const int cb1  = (cbi & 7) * 128;
  const int rb   = blockIdx.y * 128;
  const float* __restrict__ bias = dir ? b_b : b_f;

  const int sm = tid >> 1, sh = (tid & 1) * 16;          // staging row, k-half
  const int vrow = inputs[rb + sm];
  const u16* __restrict__ asrc = wkt + ((size_t)(dir * G4) + cb1 + sm) * KPAD + sh;
  const u16* __restrict__ bsrc = embf16 + (size_t)vrow * KPAD + sh;

  f32x4v acc[2][8];
#pragma unroll
  for (int bt = 0; bt < 2; ++bt)
#pragma unroll
    for (int i = 0; i < 8; ++i) acc[bt][i] = (f32x4v){0.f, 0.f, 0.f, 0.f};

  for (int kt = 0; kt < 10; ++kt) {
    const int k0 = kt * 32;
    uint4 a0v = *(const uint4*)(asrc + k0);
    uint4 a1v = *(const uint4*)(asrc + k0 + 8);
    uint4 b0v = *(const uint4*)(bsrc + k0);
    uint4 b1v = *(const uint4*)(bsrc + k0 + 8);
    *(uint4*)&As[sm * 40 + sh]     = a0v;
    *(uint4*)&As[sm * 40 + sh + 8] = a1v;
    *(uint4*)&Bs[sm * 40 + sh]     = b0v;
    *(uint4*)&Bs[sm * 40 + sh + 8] = b1v;
    __syncthreads();
    half8 bf[2];
#pragma unroll
    for (int bt = 0; bt < 2; ++bt)
      bf[bt] = *(const half8*)&Bs[(wv * 32 + bt * 16 + fl) * 40 + quad * 8];
#pragma unroll
    for (int i = 0; i < 8; ++i) {
      half8 af = *(const half8*)&As[(i * 16 + fl) * 40 + quad * 8];
      acc[0][i] = __builtin_amdgcn_mfma_f32_16x16x32_f16(af, bf[0], acc[0][i], 0, 0, 0);
      acc[1][i] = __builtin_amdgcn_mfma_f32_16x16x32_f16(af, bf[1], acc[1][i], 0, 0, 0);
    }
    __syncthreads();
  }
#pragma unroll
  for (int bt = 0; bt < 2; ++bt) {
    const int row = rb + wv * 32 + bt * 16 + fl;         // n = emb row
    u16* __restrict__ orow = xz + ((size_t)(dir * BATCH * TSEQ) + row) * G4;
#pragma unroll
    for (int i = 0; i < 8; ++i) {
      const int mb = cb1 + i * 16 + quad * 4;            // m = gate col
      const float4 bb = *(const float4*)&bias[mb];
      f32x4v v = acc[bt][i];
      uint2 pk;
      pk.x = packf16(v[0] + bb.x, v[1] + bb.y);
      pk.y = packf16(v[2] + bb.z, v[3] + bb.w);
      *(uint2*)&orow[mb] = pk;
    }
  }
}

// ---------------- K2: LSTM recurrence — v_dot4_i32_i8, 4 threads per h-index --
// Round-14: r12-r14 all landed at ~460us with VGPR_Count=84 — the allocator
// refuses to hold 128 weight dwords in arch VGPRs. r14 (inline-asm loads,
// non-rematerializable) proved the mechanism: it spilled them to AGPRs
// (occupancy tier = 212 unified regs) and pays 128 v_accvgpr_read per thread
// per step = 512 cy/SIMD — same cost as reloading, hence identical perf.
// Fix: shrink per-thread weights below the tax threshold. 4 threads per
// h-index (one gate each): 1024-thread blocks, 64 weight dwords per thread,
// pressure ~105 < 128-reg cap of launch_bounds(1024,4) -> stays in VGPRs.
// Total sdot4 issue invariant (512 cy/SIMD/step); per-thread transcendental
// count halves; combine = 3 quad shfl_xor. Lane g==1 (gate f) holds (c,h):
// partners xor1 -> i, xor3 -> g, xor2 -> o.
__global__ __launch_bounds__(1024, 4) void lstm_k(
    const u16* __restrict__ xz, const signed char* __restrict__ wr8,
    const int* __restrict__ lengths, u16* __restrict__ hcat)
{
  const int chain = blockIdx.x;
  const int dir   = chain >> 6;
  const int batch = chain & 63;
  const int tid   = threadIdx.x;
  const int g     = tid & 3;                  // gate: 0=i, 1=f, 2=g, 3=o
  const int hidx  = tid >> 2;                 // h-index 0..255
  const int col   = g * 256 + hidx;           // column in z layout [i|f|g|o]
  const float DEQ = 1.f / (512.f * 127.f);

  __shared__ __align__(16) signed char hpk[2][256];   // double-buffered h (i8)

  const signed char* __restrict__ wr8w = wr8 + (size_t)dir * G4 * HDIM;

  // this thread's Wr column: 64 dwords = 64 VGPRs
  i32x4 w[16];
#pragma unroll
  for (int j = 0; j < 16; ++j)
    w[j] = *(const i32x4*)(wr8w + (size_t)col * HDIM + j * 16);

  if (tid < 256) hpk[0][tid] = 0;

  float c = 0.f, h = 0.f;                     // live on g==1 lanes
  const int len = lengths[batch];
  const u16* __restrict__ xzb = xz + (size_t)(dir * BATCH + batch) * TSEQ * G4;
  u16* __restrict__ hrow = hcat + (size_t)batch * TSEQ * 512 + dir * 256;
  __syncthreads();

  int tt = dir ? (TSEQ - 1) : 0;
  const int dt = dir ? -1 : 1;
  const long xstride = (long)dt * G4;
  const long hstride = (long)dt * 512;
  const u16* xp = xzb + (size_t)tt * G4;
  u16* hp = hrow + (size_t)tt * 512;
  u16 x0 = xp[col];

  for (int st = 0; st < TSEQ; ++st) {
    const u16* xpn = (st == TSEQ - 1) ? xp : (xp + xstride);
    u16 xn0 = xpn[col];                       // prefetch next step's xz

    const int par = st & 1;
    const signed char* hb = &hpk[par][0];

    int a0 = 0, a1 = 0, a2 = 0, a3 = 0;       // 4 independent dep chains
#pragma unroll
    for (int j = 0; j < 16; ++j) {
      i32x4 hv = *(const i32x4*)(hb + j * 16);   // broadcast read (same addr)
      a0 = sdot4(hv[0], w[j][0], a0);
      a1 = sdot4(hv[1], w[j][1], a1);
      a2 = sdot4(hv[2], w[j][2], a2);
      a3 = sdot4(hv[3], w[j][3], a3);
    }
    const int s = (a0 + a1) + (a2 + a3);

    float z = (float)s * DEQ + f16f(x0);
    // activation: sigm for i,f,o; tanh for gate g (g==2) — one exp either way
    float earg = (g == 2) ? (-2.f * __builtin_fabsf(z)) : -z;
    float e = __expf(earg);
    float d = __builtin_amdgcn_rcpf(1.f + e);
    float act = (g == 2) ? copysignf((1.f - e) * d, z) : d;

    float ri = __shfl_xor(act, 1);            // on lane g==1: i
    float rg = __shfl_xor(act, 3);            // on lane g==1: g
    float ro = __shfl_xor(act, 2);            // on lane g==1: o
    if (g == 1) {
      float cn = fmaf(act, c, ri * rg);       // f*c + i*g
      float hn = ro * tanh_fast(cn);          // o * tanh(c)
      if (tt < len) { c = cn; h = hn; }       // masked step: hold state
      u32 hb2 = packf16(h, h);
      hp[hidx] = (u16)(hb2 & 0xffffu);
      int hq = (int)__builtin_rintf(h * 127.f);
      hpk[par ^ 1][hidx] = (signed char)hq;
    }
    __syncthreads();
    x0 = xn0; tt += dt;
    xp = xpn;
    if (st != TSEQ - 1) hp += hstride;
  }
}

// ---------------- K3: logits = hcat @ dense_W + dense_b ----------------
__global__ __launch_bounds__(256) void dense_k(
    const u16* __restrict__ hcat, const float* __restrict__ W,
    const float* __restrict__ bias, float* __restrict__ out)
{
  const int lane = threadIdx.x & 63;
  const int wv = threadIdx.x >> 6;
  const int rowbase = (blockIdx.x * 4 + wv) * 8;
  for (int rr = 0; rr < 8; ++rr) {
    const int row = rowbase + rr;
    const u16* __restrict__ hr = hcat + (size_t)row * 512;
    float hv[8];
#pragma unroll
    for (int i = 0; i < 8; ++i)
      hv[i] = f16f(hr[i * 64 + lane]);
    float myout = 0.f;
#pragma unroll
    for (int cc = 0; cc < 9; ++cc) {
      float p = 0.f;
#pragma unroll
      for (int i = 0; i < 8; ++i)
        p = fmaf(hv[i], W[(size_t)(i * 64 + lane) * 9 + cc], p);
#pragma unroll
      for (int o = 32; o > 0; o >>= 1) p += __shfl_xor(p, o);
      if (lane == cc) myout = p + bias[cc];
    }
    if (lane < 9) out[(size_t)row * 9 + lane] = myout;
  }
}

// ---------------- K4: CRF log-likelihood + trans copy ----------------
__global__ __launch_bounds__(64) void crf_k(
    const float* __restrict__ logits, const int* __restrict__ tags,
    const int* __restrict__ lengths, const float* __restrict__ trans,
    float* __restrict__ out_ll, float* __restrict__ out_trans)
{
  const int b = blockIdx.x;
  const int lane = threadIdx.x;
  const int len = lengths[b];
  const float* __restrict__ lg = logits + (size_t)b * TSEQ * NCLS;
  const int* __restrict__ tg = tags + (size_t)b * TSEQ;

  float ua = 0.f, ba = 0.f;
  for (int t = lane; t < TSEQ; t += 64) {
    int tag = tg[t];
    if (t < len) ua += lg[t * 9 + tag];
    if (t < len - 1) ba += trans[tag * 9 + tg[t + 1]];
  }
  float s = ua + ba;
#pragma unroll
  for (int o = 32; o > 0; o >>= 1) s += __shfl_xor(s, o);

  const int j = (lane < 9) ? lane : 0;
  float trc[9], alpha[9];
#pragma unroll
  for (int i = 0; i < 9; ++i) trc[i] = trans[i * 9 + j];
#pragma unroll
  for (int i = 0; i < 9; ++i) alpha[i] = lg[i];
  for (int t = 1; t < TSEQ; ++t) {
    if (t >= len) break;                 // mask is monotone
    float m = -1e30f;
#pragma unroll
    for (int i = 0; i < 9; ++i) m = fmaxf(m, alpha[i] + trc[i]);
    float ss = 0.f;
#pragma unroll
    for (int i = 0; i < 9; ++i) ss += __expf(alpha[i] + trc[i] - m);
    float nj = __logf(ss) + m + lg[t * 9 + j];
#pragma unroll
    for (int i = 0; i < 9; ++i) alpha[i] = __shfl(nj, i);
  }
  float m2 = -1e30f;
#pragma unroll
  for (int i = 0; i < 9; ++i) m2 = fmaxf(m2, alpha[i]);
  float s2 = 0.f;
#pragma unroll
  for (int i = 0; i < 9; ++i) s2 += __expf(alpha[i] - m2);
  float lse = __logf(s2) + m2;
  if (lane == 0) out_ll[b] = s - lse;
  if (b == 0)
    for (int i = lane; i < 81; i += 64) out_trans[i] = trans[i];
}

// ---------------- launch ----------------
extern "C" void kernel_launch(void* const* d_in, const int* in_sizes, int n_in,
                              void* d_out, int out_size, void* d_ws, size_t ws_size,
                              hipStream_t stream)
{
  const int*   inputs  = (const int*)d_in[0];
  const int*   lengths = (const int*)d_in[1];
  const int*   targets = (const int*)d_in[2];
  const float* emb     = (const float*)d_in[3];
  const float* Wk_f    = (const float*)d_in[4];
  const float* Wr_f    = (const float*)d_in[5];
  const float* b_f     = (const float*)d_in[6];
  const float* Wk_b    = (const float*)d_in[7];
  const float* Wr_b    = (const float*)d_in[8];
  const float* b_b     = (const float*)d_in[9];
  const float* dense_W = (const float*)d_in[10];
  const float* dense_b = (const float*)d_in[11];
  const float* trans   = (const float*)d_in[12];

  char* ws = (char*)d_ws;
  u16*         wkt    = (u16*)ws;                              //  1,310,720 B
  signed char* wr8    = (signed char*)(ws + 1310720ull);       //    524,288 B
  u16*         embf16 = (u16*)(ws + 1835008ull);               // 19,200,000 B
  u16*         xz     = (u16*)(ws + 1835008ull + 19200000ull); // 134,217,728 B
  u16*         hcat   = (u16*)(ws + 1835008ull + 19200000ull + 134217728ull); // 33,554,432 B

  float* out_logits = (float*)d_out;
  float* out_ll     = out_logits + (size_t)BATCH * TSEQ * NCLS;
  float* out_trans  = out_ll + BATCH;

  hipLaunchKernelGGL(embcvt_k, dim3(1875), dim3(256), 0, stream, emb, embf16);
  hipLaunchKernelGGL(wkt_k, dim3(64, 2), dim3(256), 0, stream, Wk_f, Wk_b, wkt);
  hipLaunchKernelGGL(wr8_k, dim3(64, 2), dim3(256), 0, stream, Wr_f, Wr_b, wr8);
  hipLaunchKernelGGL(xz_gemm_k, dim3(16, 256), dim3(256), 0, stream,
                     inputs, wkt, embf16, b_f, b_b, xz);
  hipLaunchKernelGGL(lstm_k, dim3(128), dim3(1024), 0, stream,
                     xz, wr8, lengths, hcat);
  hipLaunchKernelGGL(dense_k, dim3(1024), dim3(256), 0, stream,
                     hcat, dense_W, dense_b, out_logits);
  hipLaunchKernelGGL(crf_k, dim3(64), dim3(64), 0, stream,
                     out_logits, targets, lengths, trans, out_ll, out_trans);
}

// Round 6
// 736.280 us; speedup vs baseline: 1.1718x; 1.1718x over previous
//
#include <hip/hip_runtime.h>
#include <cstdint>
#include <cstddef>

typedef unsigned int  u32;
typedef unsigned short u16;
typedef _Float16 f16;
typedef _Float16 f16x2 __attribute__((ext_vector_type(2)));
typedef _Float16 half8 __attribute__((ext_vector_type(8)));
typedef float    f32x4v __attribute__((ext_vector_type(4)));
typedef int      i32x4 __attribute__((ext_vector_type(4)));

#define BATCH 64
#define TSEQ  512
#define DEMB  300
#define KPAD  320
#define HDIM  256
#define G4    1024
#define NCLS  9

__device__ __forceinline__ u32 packf16(float a, float b) {
  f16x2 v; v.x = (f16)a; v.y = (f16)b;
  return __builtin_bit_cast(u32, v);
}
__device__ __forceinline__ float f16f(u16 x) {
  return (float)__builtin_bit_cast(f16, x);
}
__device__ __forceinline__ float sigm_fast(float x) {
  return __builtin_amdgcn_rcpf(1.f + __expf(-x));
}
__device__ __forceinline__ float tanh_fast(float x) {
  float ax = __builtin_fabsf(x);
  float e = __expf(-2.f * ax);
  float t = (1.f - e) * __builtin_amdgcn_rcpf(1.f + e);
  return copysignf(t, x);
}

// ---------------- P1: embf16[v][320] = f16(emb[v][0..299]), zero-pad 300..319 ----
__global__ __launch_bounds__(256) void embcvt_k(const float* __restrict__ emb,
                                                u16* __restrict__ out) {
  const int v  = blockIdx.x * 16 + (threadIdx.x >> 4);
  const int kc = threadIdx.x & 15;
  u32* __restrict__ dst = (u32*)(out + (size_t)v * KPAD + kc * 20);
  if (kc < 15) {
    const float* __restrict__ src = emb + (size_t)v * DEMB + kc * 20;
    float tmp[20];
#pragma unroll
    for (int j = 0; j < 20; ++j) tmp[j] = src[j];
#pragma unroll
    for (int j = 0; j < 10; ++j) dst[j] = packf16(tmp[2 * j], tmp[2 * j + 1]);
  } else {
#pragma unroll
    for (int j = 0; j < 10; ++j) dst[j] = 0u;
  }
}

// ---------------- P2: wkt[dir][col][320] = f16(Wk[k][col]), zero-pad k>=300 -----
__global__ __launch_bounds__(256) void wkt_k(const float* __restrict__ Wk_f,
                                             const float* __restrict__ Wk_b,
                                             u16* __restrict__ wkt) {
  const int dir = blockIdx.y;
  const float* __restrict__ Wk = dir ? Wk_b : Wk_f;
  const int col = blockIdx.x * 16 + (threadIdx.x >> 4);
  const int kc  = threadIdx.x & 15;
  u32* __restrict__ dst = (u32*)(wkt + ((size_t)dir * G4 + col) * KPAD + kc * 20);
  if (kc < 15) {
    float tmp[20];
#pragma unroll
    for (int j = 0; j < 20; ++j) tmp[j] = Wk[(size_t)(kc * 20 + j) * G4 + col];
#pragma unroll
    for (int j = 0; j < 10; ++j) dst[j] = packf16(tmp[2 * j], tmp[2 * j + 1]);
  } else {
#pragma unroll
    for (int j = 0; j < 10; ++j) dst[j] = 0u;
  }
}

// ---------------- P3: wr8[dir][col][256] = int8(Wr[k][col] * 512), k-major ----
__global__ __launch_bounds__(256) void wr8_k(const float* __restrict__ Wr_f,
                                             const float* __restrict__ Wr_b,
                                             signed char* __restrict__ wr8) {
  const int dir = blockIdx.y;
  const float* __restrict__ Wr = dir ? Wr_b : Wr_f;
  const int col = blockIdx.x * 16 + (threadIdx.x >> 4);
  const int k0  = (threadIdx.x & 15) * 16;
  float tmp[16];
#pragma unroll
  for (int j = 0; j < 16; ++j) tmp[j] = Wr[(size_t)(k0 + j) * G4 + col];
  u32 pw[4];
#pragma unroll
  for (int jj = 0; jj < 4; ++jj) {
    u32 p = 0;
#pragma unroll
    for (int b = 0; b < 4; ++b) {
      int q = (int)__builtin_rintf(tmp[4 * jj + b] * 512.f);
      q = q > 127 ? 127 : (q < -127 ? -127 : q);
      p |= ((u32)(q & 255)) << (8 * b);
    }
    pw[jj] = p;
  }
  *(uint4*)(wr8 + ((size_t)dir * G4 + col) * HDIM + k0) =
      make_uint4(pw[0], pw[1], pw[2], pw[3]);
}

// ---------------- K1: xz = emb[inputs] @ Wk + b  (MFMA f16) ----------------
__global__ __launch_bounds__(256) void xz_gemm_k(
    const int* __restrict__ inputs, const u16* __restrict__ wkt,
    const u16* __restrict__ embf16, const float* __restrict__ b_f,
    const float* __restrict__ b_b, u16* __restrict__ xz)
{
  __shared__ __align__(16) u16 As[128 * 40];   // [m][k], k-major, pad 32->40
  __shared__ __align__(16) u16 Bs[128 * 40];   // [n][k], k-major
  const int tid  = threadIdx.x;
  const int wv   = tid >> 6, lane = tid & 63;
  const int quad = lane >> 4, fl = lane & 15;
  const int cbi  = blockIdx.x;                 // 0..15
  const int dir  = cbi >> 3;
  const int cb1  = (cbi & 7) * 128;
  const int rb   = blockIdx.y * 128;
  const float* __restrict__ bias = dir ? b_b : b_f;

  const int sm = tid >> 1, sh = (tid & 1) * 16;          // staging row, k-half
  const int vrow = inputs[rb + sm];
  const u16* __restrict__ asrc = wkt + ((size_t)(dir * G4) + cb1 + sm) * KPAD + sh;
  const u16* __restrict__ bsrc = embf16 + (size_t)vrow * KPAD + sh;

  f32x4v acc[2][8];
#pragma unroll
  for (int bt = 0; bt < 2; ++bt)
#pragma unroll
    for (int i = 0; i < 8; ++i) acc[bt][i] = (f32x4v){0.f, 0.f, 0.f, 0.f};

  for (int kt = 0; kt < 10; ++kt) {
    const int k0 = kt * 32;
    uint4 a0v = *(const uint4*)(asrc + k0);
    uint4 a1v = *(const uint4*)(asrc + k0 + 8);
    uint4 b0v = *(const uint4*)(bsrc + k0);
    uint4 b1v = *(const uint4*)(bsrc + k0 + 8);
    *(uint4*)&As[sm * 40 + sh]     = a0v;
    *(uint4*)&As[sm * 40 + sh + 8] = a1v;
    *(uint4*)&Bs[sm * 40 + sh]     = b0v;
    *(uint4*)&Bs[sm * 40 + sh + 8] = b1v;
    __syncthreads();
    half8 bf[2];
#pragma unroll
    for (int bt = 0; bt < 2; ++bt)
      bf[bt] = *(const half8*)&Bs[(wv * 32 + bt * 16 + fl) * 40 + quad * 8];
#pragma unroll
    for (int i = 0; i < 8; ++i) {
      half8 af = *(const half8*)&As[(i * 16 + fl) * 40 + quad * 8];
      acc[0][i] = __builtin_amdgcn_mfma_f32_16x16x32_f16(af, bf[0], acc[0][i], 0, 0, 0);
      acc[1][i] = __builtin_amdgcn_mfma_f32_16x16x32_f16(af, bf[1], acc[1][i], 0, 0, 0);
    }
    __syncthreads();
  }
#pragma unroll
  for (int bt = 0; bt < 2; ++bt) {
    const int row = rb + wv * 32 + bt * 16 + fl;         // n = emb row
    u16* __restrict__ orow = xz + ((size_t)(dir * BATCH * TSEQ) + row) * G4;
#pragma unroll
    for (int i = 0; i < 8; ++i) {
      const int mb = cb1 + i * 16 + quad * 4;            // m = gate col
      const float4 bb = *(const float4*)&bias[mb];
      f32x4v v = acc[bt][i];
      uint2 pk;
      pk.x = packf16(v[0] + bb.x, v[1] + bb.y);
      pk.y = packf16(v[2] + bb.z, v[3] + bb.w);
      *(uint2*)&orow[mb] = pk;
    }
  }
}

// ---------------- K2: LSTM recurrence — int8 MFMA, 2 waves/SIMD --------------
// RESTORED r0 structure (measured 400us): weights as "+a"-pinned AGPR frags
// consumed natively by MFMA — the ONLY residency scheme the allocator honors
// (r2-r5 evidence: every VALU/sdot4 variant got weights demoted to L2
// streaming or AGPR-move tax, all ~460-550us). Surgical additions this round:
//  (1) s_setprio(1) around the 32-MFMA cluster;
//  (2) gate split across the redundant quad-pairs: quads 2,3 ("B") compute
//      i=sigm, g=tanh and ship i*g via shfl_xor(.,32); quads 0,1 ("A", the
//      writers, holding c/h) compute f=sigm, o=sigm and the c/h update.
//      Cuts per-lane transcendentals 5 -> ~2.5 and xz loads 4 -> 2 per step.
// Wave w owns h-indices [32w, 32w+32) x 4 gates: 8 tiles x 4 k-chunks =
// 32 frags = 128 AGPRs pinned "+a". C-layout gives every quad all tiles'
// z at col=l15 (A-rows replicated), so both quad-pairs see all gate sums.
#define MFI(a, b, c) __builtin_amdgcn_mfma_i32_16x16x64_i8(a, b, c, 0, 0, 0)
#define LD8(g, ct, kc) (*(const i32x4*)(wr8w + (size_t)((g) * 256 + 32 * w + (ct) * 16 + l15) * HDIM + (kc) * 64 + q16))
#define DECL8(g, ct) \
  i32x4 W##g##ct##_0 = LD8(g, ct, 0), W##g##ct##_1 = LD8(g, ct, 1), \
        W##g##ct##_2 = LD8(g, ct, 2), W##g##ct##_3 = LD8(g, ct, 3); \
  asm volatile("" : "+a"(W##g##ct##_0), "+a"(W##g##ct##_1), \
                    "+a"(W##g##ct##_2), "+a"(W##g##ct##_3));
#define TILE(g, ct) \
  i32x4 ac##g##ct = (i32x4){0, 0, 0, 0}; \
  ac##g##ct = MFI(af0, W##g##ct##_0, ac##g##ct); \
  ac##g##ct = MFI(af1, W##g##ct##_1, ac##g##ct); \
  ac##g##ct = MFI(af2, W##g##ct##_2, ac##g##ct); \
  ac##g##ct = MFI(af3, W##g##ct##_3, ac##g##ct);

__global__ __launch_bounds__(512, 2) void lstm_k(
    const u16* __restrict__ xz, const signed char* __restrict__ wr8,
    const int* __restrict__ lengths, u16* __restrict__ hcat)
{
  const int chain = blockIdx.x;
  const int dir   = chain >> 6;
  const int batch = chain & 63;
  const int tid  = threadIdx.x;
  const int w    = tid >> 6;
  const int lane = tid & 63;
  const int quad = lane >> 4, l15 = lane & 15;
  const int q16  = quad * 16;
  const int ctsel = quad & 1;
  const int j    = 32 * w + ctsel * 16 + l15;   // this thread's h-index
  const int wr   = quad < 2;                    // "A" lanes: writers, hold c/h
  const int isB  = quad >= 2;                   // "B" lanes: compute i, g
  const float DEQ = 1.f / (512.f * 127.f);

  __shared__ __align__(16) signed char hpk[2][256];   // double-buffered h (i8)

  const signed char* __restrict__ wr8w = wr8 + (size_t)dir * G4 * HDIM;

  // 8 tiles x 4 k-chunks = 32 frags = 128 AGPRs, pinned
  DECL8(0, 0) DECL8(0, 1) DECL8(1, 0) DECL8(1, 1)
  DECL8(2, 0) DECL8(2, 1) DECL8(3, 0) DECL8(3, 1)

  if (tid < 256) hpk[0][tid] = 0;

  float c = 0.f, h = 0.f;
  const int len = lengths[batch];
  const u16* __restrict__ xzb = xz + (size_t)(dir * BATCH + batch) * TSEQ * G4;
  u16* __restrict__ hrow = hcat + (size_t)batch * TSEQ * 512 + dir * 256;
  __syncthreads();

  // per-lane gate columns: B -> gates i (j), g (512+j); A -> f (256+j), o (768+j)
  const int colP = (isB ? 0 : 256) + j;
  const int colQ = (isB ? 512 : 768) + j;

  int tt = dir ? (TSEQ - 1) : 0;
  const int dt = dir ? -1 : 1;
  u16 x0 = xzb[(size_t)tt * G4 + colP];
  u16 x1 = xzb[(size_t)tt * G4 + colQ];

  for (int st = 0; st < TSEQ; ++st) {
    const int ttn = (st == TSEQ - 1) ? tt : tt + dt;
    u16 xn0 = xzb[(size_t)ttn * G4 + colP];       // prefetch next step's xz
    u16 xn1 = xzb[(size_t)ttn * G4 + colQ];

    const int par = st & 1;
    const signed char* hb = &hpk[par][0];
    // A-frags: h replicated across rows; lane reads k = kc*64 + quad*16 .. +15
    i32x4 af0 = *(const i32x4*)(hb + q16);
    i32x4 af1 = *(const i32x4*)(hb + 64 + q16);
    i32x4 af2 = *(const i32x4*)(hb + 128 + q16);
    i32x4 af3 = *(const i32x4*)(hb + 192 + q16);

    __builtin_amdgcn_s_setprio(1);
    TILE(0, 0) TILE(0, 1)    // gate i, col-subtiles 0,1
    TILE(1, 0) TILE(1, 1)    // gate f
    TILE(2, 0) TILE(2, 1)    // gate g
    TILE(3, 0) TILE(3, 1)    // gate o
    __builtin_amdgcn_s_setprio(0);

    // every quad holds every tile's z at col=l15 (A-rows replicated):
    // B-lanes pick gates i,g; A-lanes pick gates f,o.
    int rP = ctsel ? (isB ? ac01[0] : ac11[0]) : (isB ? ac00[0] : ac10[0]);
    int rQ = ctsel ? (isB ? ac21[0] : ac31[0]) : (isB ? ac20[0] : ac30[0]);

    float zP = (float)rP * DEQ + f16f(x0);    // B: zi ; A: zf
    float zQ = (float)rQ * DEQ + f16f(x1);    // B: zg ; A: zo
    float aP = sigm_fast(zP);                 // B: i  ; A: f
    // aQ: tanh on B (gate g), sigmoid on A (gate o) — one exp either way
    float earg = isB ? (-2.f * __builtin_fabsf(zQ)) : -zQ;
    float e = __expf(earg);
    float d = __builtin_amdgcn_rcpf(1.f + e);
    float aQ = isB ? copysignf((1.f - e) * d, zQ) : d;

    float ig = aP * aQ;                       // meaningful on B lanes
    float ig_in = __shfl_xor(ig, 32);         // A receives partner B's i*g
    if (wr) {
      float cn = fmaf(aP, c, ig_in);          // f*c + i*g
      float hn = aQ * tanh_fast(cn);          // o * tanh(c)
      if (tt < len) { c = cn; h = hn; }       // masked step: hold state
      u32 hb2 = packf16(h, h);
      hrow[(size_t)tt * 512 + j] = (u16)(hb2 & 0xffffu);
      int hq = (int)__builtin_rintf(h * 127.f);
      hpk[par ^ 1][j] = (signed char)hq;
    }
    __syncthreads();
    x0 = xn0; x1 = xn1; tt = ttn;
  }
}

// ---------------- K3: logits = hcat @ dense_W + dense_b ----------------
__global__ __launch_bounds__(256) void dense_k(
    const u16* __restrict__ hcat, const float* __restrict__ W,
    const float* __restrict__ bias, float* __restrict__ out)
{
  const int lane = threadIdx.x & 63;
  const int wv = threadIdx.x >> 6;
  const int rowbase = (blockIdx.x * 4 + wv) * 8;
  for (int rr = 0; rr < 8; ++rr) {
    const int row = rowbase + rr;
    const u16* __restrict__ hr = hcat + (size_t)row * 512;
    float hv[8];
#pragma unroll
    for (int i = 0; i < 8; ++i)
      hv[i] = f16f(hr[i * 64 + lane]);
    float myout = 0.f;
#pragma unroll
    for (int cc = 0; cc < 9; ++cc) {
      float p = 0.f;
#pragma unroll
      for (int i = 0; i < 8; ++i)
        p = fmaf(hv[i], W[(size_t)(i * 64 + lane) * 9 + cc], p);
#pragma unroll
      for (int o = 32; o > 0; o >>= 1) p += __shfl_xor(p, o);
      if (lane == cc) myout = p + bias[cc];
    }
    if (lane < 9) out[(size_t)row * 9 + lane] = myout;
  }
}

// ---------------- K4: CRF log-likelihood + trans copy ----------------
__global__ __launch_bounds__(64) void crf_k(
    const float* __restrict__ logits, const int* __restrict__ tags,
    const int* __restrict__ lengths, const float* __restrict__ trans,
    float* __restrict__ out_ll, float* __restrict__ out_trans)
{
  const int b = blockIdx.x;
  const int lane = threadIdx.x;
  const int len = lengths[b];
  const float* __restrict__ lg = logits + (size_t)b * TSEQ * NCLS;
  const int* __restrict__ tg = tags + (size_t)b * TSEQ;

  float ua = 0.f, ba = 0.f;
  for (int t = lane; t < TSEQ; t += 64) {
    int tag = tg[t];
    if (t < len) ua += lg[t * 9 + tag];
    if (t < len - 1) ba += trans[tag * 9 + tg[t + 1]];
  }
  float s = ua + ba;
#pragma unroll
  for (int o = 32; o > 0; o >>= 1) s += __shfl_xor(s, o);

  const int j = (lane < 9) ? lane : 0;
  float trc[9], alpha[9];
#pragma unroll
  for (int i = 0; i < 9; ++i) trc[i] = trans[i * 9 + j];
#pragma unroll
  for (int i = 0; i < 9; ++i) alpha[i] = lg[i];
  for (int t = 1; t < TSEQ; ++t) {
    if (t >= len) break;                 // mask is monotone
    float m = -1e30f;
#pragma unroll
    for (int i = 0; i < 9; ++i) m = fmaxf(m, alpha[i] + trc[i]);
    float ss = 0.f;
#pragma unroll
    for (int i = 0; i < 9; ++i) ss += __expf(alpha[i] + trc[i] - m);
    float nj = __logf(ss) + m + lg[t * 9 + j];
#pragma unroll
    for (int i = 0; i < 9; ++i) alpha[i] = __shfl(nj, i);
  }
  float m2 = -1e30f;
#pragma unroll
  for (int i = 0; i < 9; ++i) m2 = fmaxf(m2, alpha[i]);
  float s2 = 0.f;
#pragma unroll
  for (int i = 0; i < 9; ++i) s2 += __expf(alpha[i] - m2);
  float lse = __logf(s2) + m2;
  if (lane == 0) out_ll[b] = s - lse;
  if (b == 0)
    for (int i = lane; i < 81; i += 64) out_trans[i] = trans[i];
}

// ---------------- launch ----------------
extern "C" void kernel_launch(void* const* d_in, const int* in_sizes, int n_in,
                              void* d_out, int out_size, void* d_ws, size_t ws_size,
                              hipStream_t stream)
{
  const int*   inputs  = (const int*)d_in[0];
  const int*   lengths = (const int*)d_in[1];
  const int*   targets = (const int*)d_in[2];
  const float* emb     = (const float*)d_in[3];
  const float* Wk_f    = (const float*)d_in[4];
  const float* Wr_f    = (const float*)d_in[5];
  const float* b_f     = (const float*)d_in[6];
  const float* Wk_b    = (const float*)d_in[7];
  const float* Wr_b    = (const float*)d_in[8];
  const float* b_b     = (const float*)d_in[9];
  const float* dense_W = (const float*)d_in[10];
  const float* dense_b = (const float*)d_in[11];
  const float* trans   = (const float*)d_in[12];

  char* ws = (char*)d_ws;
  u16*         wkt    = (u16*)ws;                              //  1,310,720 B
  signed char* wr8    = (signed char*)(ws + 1310720ull);       //    524,288 B
  u16*         embf16 = (u16*)(ws + 1835008ull);               // 19,200,000 B
  u16*         xz     = (u16*)(ws + 1835008ull + 19200000ull); // 134,217,728 B
  u16*         hcat   = (u16*)(ws + 1835008ull + 19200000ull + 134217728ull); // 33,554,432 B

  float* out_logits = (float*)d_out;
  float* out_ll     = out_logits + (size_t)BATCH * TSEQ * NCLS;
  float* out_trans  = out_ll + BATCH;

  hipLaunchKernelGGL(embcvt_k, dim3(1875), dim3(256), 0, stream, emb, embf16);
  hipLaunchKernelGGL(wkt_k, dim3(64, 2), dim3(256), 0, stream, Wk_f, Wk_b, wkt);
  hipLaunchKernelGGL(wr8_k, dim3(64, 2), dim3(256), 0, stream, Wr_f, Wr_b, wr8);
  hipLaunchKernelGGL(xz_gemm_k, dim3(16, 256), dim3(256), 0, stream,
                     inputs, wkt, embf16, b_f, b_b, xz);
  hipLaunchKernelGGL(lstm_k, dim3(128), dim3(512), 0, stream,
                     xz, wr8, lengths, hcat);
  hipLaunchKernelGGL(dense_k, dim3(1024), dim3(256), 0, stream,
                     hcat, dense_W, dense_b, out_logits);
  hipLaunchKernelGGL(crf_k, dim3(64), dim3(64), 0, stream,
                     out_logits, targets, lengths, trans, out_ll, out_trans);
}

// Round 8
// 708.051 us; speedup vs baseline: 1.2185x; 1.0399x over previous
//
#include <hip/hip_runtime.h>
#include <cstdint>
#include <cstddef>

typedef unsigned int  u32;
typedef unsigned short u16;
typedef _Float16 f16;
typedef _Float16 f16x2 __attribute__((ext_vector_type(2)));
typedef _Float16 half8 __attribute__((ext_vector_type(8)));
typedef float    f32x4v __attribute__((ext_vector_type(4)));
typedef int      i32x4 __attribute__((ext_vector_type(4)));

#define BATCH 64
#define TSEQ  512
#define DEMB  300
#define KPAD  320
#define HDIM  256
#define G4    1024
#define NCLS  9

__device__ __forceinline__ u32 packf16(float a, float b) {
  f16x2 v; v.x = (f16)a; v.y = (f16)b;
  return __builtin_bit_cast(u32, v);
}
__device__ __forceinline__ float f16f(u16 x) {
  return (float)__builtin_bit_cast(f16, x);
}
__device__ __forceinline__ float sigm_fast(float x) {
  return __builtin_amdgcn_rcpf(1.f + __expf(-x));
}
__device__ __forceinline__ float tanh_fast(float x) {
  float ax = __builtin_fabsf(x);
  float e = __expf(-2.f * ax);
  float t = (1.f - e) * __builtin_amdgcn_rcpf(1.f + e);
  return copysignf(t, x);
}

// ---------------- P1: embf16[v][320] = f16(emb[v][0..299]), zero-pad 300..319 ----
__global__ __launch_bounds__(256) void embcvt_k(const float* __restrict__ emb,
                                                u16* __restrict__ out) {
  const int v  = blockIdx.x * 16 + (threadIdx.x >> 4);
  const int kc = threadIdx.x & 15;
  u32* __restrict__ dst = (u32*)(out + (size_t)v * KPAD + kc * 20);
  if (kc < 15) {
    const float* __restrict__ src = emb + (size_t)v * DEMB + kc * 20;
    float tmp[20];
#pragma unroll
    for (int j = 0; j < 20; ++j) tmp[j] = src[j];
#pragma unroll
    for (int j = 0; j < 10; ++j) dst[j] = packf16(tmp[2 * j], tmp[2 * j + 1]);
  } else {
#pragma unroll
    for (int j = 0; j < 10; ++j) dst[j] = 0u;
  }
}

// ---------------- P2: wkt[dir][col][320] = f16(Wk[k][col]), zero-pad k>=300 -----
__global__ __launch_bounds__(256) void wkt_k(const float* __restrict__ Wk_f,
                                             const float* __restrict__ Wk_b,
                                             u16* __restrict__ wkt) {
  const int dir = blockIdx.y;
  const float* __restrict__ Wk = dir ? Wk_b : Wk_f;
  const int col = blockIdx.x * 16 + (threadIdx.x >> 4);
  const int kc  = threadIdx.x & 15;
  u32* __restrict__ dst = (u32*)(wkt + ((size_t)dir * G4 + col) * KPAD + kc * 20);
  if (kc < 15) {
    float tmp[20];
#pragma unroll
    for (int j = 0; j < 20; ++j) tmp[j] = Wk[(size_t)(kc * 20 + j) * G4 + col];
#pragma unroll
    for (int j = 0; j < 10; ++j) dst[j] = packf16(tmp[2 * j], tmp[2 * j + 1]);
  } else {
#pragma unroll
    for (int j = 0; j < 10; ++j) dst[j] = 0u;
  }
}

// ---------------- P3: wr8[dir][col][256] = int8(Wr[k][col] * 512), k-major ----
__global__ __launch_bounds__(256) void wr8_k(const float* __restrict__ Wr_f,
                                             const float* __restrict__ Wr_b,
                                             signed char* __restrict__ wr8) {
  const int dir = blockIdx.y;
  const float* __restrict__ Wr = dir ? Wr_b : Wr_f;
  const int col = blockIdx.x * 16 + (threadIdx.x >> 4);
  const int k0  = (threadIdx.x & 15) * 16;
  float tmp[16];
#pragma unroll
  for (int j = 0; j < 16; ++j) tmp[j] = Wr[(size_t)(k0 + j) * G4 + col];
  u32 pw[4];
#pragma unroll
  for (int jj = 0; jj < 4; ++jj) {
    u32 p = 0;
#pragma unroll
    for (int b = 0; b < 4; ++b) {
      int q = (int)__builtin_rintf(tmp[4 * jj + b] * 512.f);
      q = q > 127 ? 127 : (q < -127 ? -127 : q);
      p |= ((u32)(q & 255)) << (8 * b);
    }
    pw[jj] = p;
  }
  *(uint4*)(wr8 + ((size_t)dir * G4 + col) * HDIM + k0) =
      make_uint4(pw[0], pw[1], pw[2], pw[3]);
}

// ---------------- K1: xz = emb[inputs] @ Wk + b  (MFMA f16) ----------------
// Round-7 (resubmit after infra failure): xz was LDS-pipe-bound (40 ds_read +
// 16 ds_write vs only ~310cy of MFMA per block-kt) with 2 barriers x 10 kts.
// Changes: (a) 64x64 per-wave footprint (2x2 wave grid, acc[4][4]) -> 8 frag
// reads per 16 MFMAs; (b) double-buffered LDS: globals for kt+1 issued before
// kt's MFMA phase, ds_write to the ALTERNATE buffer after, ONE barrier per kt
// (write->read hazard covered: readers of cur finished before barrier;
// writers touch cur^1; next iter reads cur^1 after barrier, writes cur after).
__global__ __launch_bounds__(256) void xz_gemm_k(
    const int* __restrict__ inputs, const u16* __restrict__ wkt,
    const u16* __restrict__ embf16, const float* __restrict__ b_f,
    const float* __restrict__ b_b, u16* __restrict__ xz)
{
  __shared__ __align__(16) u16 As[2][128 * 40];   // [m][k], k-major, pad 32->40
  __shared__ __align__(16) u16 Bs[2][128 * 40];   // [n][k], k-major
  const int tid  = threadIdx.x;
  const int wv   = tid >> 6, lane = tid & 63;
  const int quad = lane >> 4, fl = lane & 15;
  const int wm   = wv & 1;                     // wave m-offset: 64*wm
  const int wn   = wv >> 1;                    // wave n-offset: 64*wn
  const int cbi  = blockIdx.x;                 // 0..15
  const int dir  = cbi >> 3;
  const int cb1  = (cbi & 7) * 128;
  const int rb   = blockIdx.y * 128;
  const float* __restrict__ bias = dir ? b_b : b_f;

  const int sm = tid >> 1, sh = (tid & 1) * 16;          // staging row, k-half
  const int vrow = inputs[rb + sm];
  const u16* __restrict__ asrc = wkt + ((size_t)(dir * G4) + cb1 + sm) * KPAD + sh;
  const u16* __restrict__ bsrc = embf16 + (size_t)vrow * KPAD + sh;

  f32x4v acc[4][4];                            // [i (m)][bt (n)]
#pragma unroll
  for (int i = 0; i < 4; ++i)
#pragma unroll
    for (int bt = 0; bt < 4; ++bt) acc[i][bt] = (f32x4v){0.f, 0.f, 0.f, 0.f};

  // prologue: stage kt=0 into buffer 0
  {
    uint4 a0v = *(const uint4*)(asrc);
    uint4 a1v = *(const uint4*)(asrc + 8);
    uint4 b0v = *(const uint4*)(bsrc);
    uint4 b1v = *(const uint4*)(bsrc + 8);
    *(uint4*)&As[0][sm * 40 + sh]     = a0v;
    *(uint4*)&As[0][sm * 40 + sh + 8] = a1v;
    *(uint4*)&Bs[0][sm * 40 + sh]     = b0v;
    *(uint4*)&Bs[0][sm * 40 + sh + 8] = b1v;
  }
  __syncthreads();

  for (int kt = 0; kt < 10; ++kt) {
    const int cur = kt & 1;
    uint4 na0, na1, nb0, nb1;
    if (kt < 9) {                              // issue next tile's globals early
      const int k0 = (kt + 1) * 32;
      na0 = *(const uint4*)(asrc + k0);
      na1 = *(const uint4*)(asrc + k0 + 8);
      nb0 = *(const uint4*)(bsrc + k0);
      nb1 = *(const uint4*)(bsrc + k0 + 8);
    }

    half8 af[4], bf[4];
#pragma unroll
    for (int i = 0; i < 4; ++i)
      af[i] = *(const half8*)&As[cur][(wm * 64 + i * 16 + fl) * 40 + quad * 8];
#pragma unroll
    for (int bt = 0; bt < 4; ++bt)
      bf[bt] = *(const half8*)&Bs[cur][(wn * 64 + bt * 16 + fl) * 40 + quad * 8];
#pragma unroll
    for (int i = 0; i < 4; ++i)
#pragma unroll
      for (int bt = 0; bt < 4; ++bt)
        acc[i][bt] = __builtin_amdgcn_mfma_f32_16x16x32_f16(af[i], bf[bt], acc[i][bt], 0, 0, 0);

    if (kt < 9) {                              // write next tile to alternate buf
      const int alt = cur ^ 1;
      *(uint4*)&As[alt][sm * 40 + sh]     = na0;
      *(uint4*)&As[alt][sm * 40 + sh + 8] = na1;
      *(uint4*)&Bs[alt][sm * 40 + sh]     = nb0;
      *(uint4*)&Bs[alt][sm * 40 + sh + 8] = nb1;
    }
    __syncthreads();
  }

#pragma unroll
  for (int bt = 0; bt < 4; ++bt) {
    const int row = rb + wn * 64 + bt * 16 + fl;         // n = emb row
    u16* __restrict__ orow = xz + ((size_t)(dir * BATCH * TSEQ) + row) * G4;
#pragma unroll
    for (int i = 0; i < 4; ++i) {
      const int mb = cb1 + wm * 64 + i * 16 + quad * 4;  // m = gate col
      const float4 bb = *(const float4*)&bias[mb];
      f32x4v v = acc[i][bt];
      uint2 pk;
      pk.x = packf16(v[0] + bb.x, v[1] + bb.y);
      pk.y = packf16(v[2] + bb.z, v[3] + bb.w);
      *(uint2*)&orow[mb] = pk;
    }
  }
}

// ---------------- K2: LSTM recurrence — int8 MFMA, 2 waves/SIMD --------------
// EXACT r0 structure (measured 400us — best). r6 A/B: gate-split+setprio was
// −2.5% (tail is latency-bound, not VALU-bound; setprio hurts lockstep blocks;
// shfl_xor(.,32) sat in the serial c/h chain). Weights live as "+a"-pinned
// AGPR frags consumed natively by MFMA — the only residency scheme the
// allocator honors (r2-r5 evidence). Wave w owns h-indices [32w,32w+32) for
// all 4 gates: 8 tiles x 4 k-chunks = 32 frags = 128 AGPRs pinned.
#define MFI(a, b, c) __builtin_amdgcn_mfma_i32_16x16x64_i8(a, b, c, 0, 0, 0)
#define LD8(g, ct, kc) (*(const i32x4*)(wr8w + (size_t)((g) * 256 + 32 * w + (ct) * 16 + l15) * HDIM + (kc) * 64 + q16))
#define DECL8(g, ct) \
  i32x4 W##g##ct##_0 = LD8(g, ct, 0), W##g##ct##_1 = LD8(g, ct, 1), \
        W##g##ct##_2 = LD8(g, ct, 2), W##g##ct##_3 = LD8(g, ct, 3); \
  asm volatile("" : "+a"(W##g##ct##_0), "+a"(W##g##ct##_1), \
                    "+a"(W##g##ct##_2), "+a"(W##g##ct##_3));
#define TILE(g, ct) \
  i32x4 ac##g##ct = (i32x4){0, 0, 0, 0}; \
  ac##g##ct = MFI(af0, W##g##ct##_0, ac##g##ct); \
  ac##g##ct = MFI(af1, W##g##ct##_1, ac##g##ct); \
  ac##g##ct = MFI(af2, W##g##ct##_2, ac##g##ct); \
  ac##g##ct = MFI(af3, W##g##ct##_3, ac##g##ct);

__global__ __launch_bounds__(512, 2) void lstm_k(
    const u16* __restrict__ xz, const signed char* __restrict__ wr8,
    const int* __restrict__ lengths, u16* __restrict__ hcat)
{
  const int chain = blockIdx.x;
  const int dir   = chain >> 6;
  const int batch = chain & 63;
  const int tid  = threadIdx.x;
  const int w    = tid >> 6;
  const int lane = tid & 63;
  const int quad = lane >> 4, l15 = lane & 15;
  const int q16  = quad * 16;
  const int ctsel = quad & 1;
  const int j    = 32 * w + ctsel * 16 + l15;   // this thread's h-index
  const int wr   = quad < 2;                    // writer lane for index j
  const float DEQ = 1.f / (512.f * 127.f);

  __shared__ __align__(16) signed char hpk[2][256];   // double-buffered h (i8)

  const signed char* __restrict__ wr8w = wr8 + (size_t)dir * G4 * HDIM;

  // 8 tiles x 4 k-chunks = 32 frags = 128 AGPRs, pinned
  DECL8(0, 0) DECL8(0, 1) DECL8(1, 0) DECL8(1, 1)
  DECL8(2, 0) DECL8(2, 1) DECL8(3, 0) DECL8(3, 1)

  if (tid < 256) hpk[0][tid] = 0;

  float c = 0.f, h = 0.f;
  const int len = lengths[batch];
  const u16* __restrict__ xzb = xz + (size_t)(dir * BATCH + batch) * TSEQ * G4;
  u16* __restrict__ hrow = hcat + (size_t)batch * TSEQ * 512 + dir * 256;
  __syncthreads();

  int tt = dir ? (TSEQ - 1) : 0;
  const int dt = dir ? -1 : 1;
  u16 x0 = xzb[(size_t)tt * G4 + j];
  u16 x1 = xzb[(size_t)tt * G4 + 256 + j];
  u16 x2 = xzb[(size_t)tt * G4 + 512 + j];
  u16 x3 = xzb[(size_t)tt * G4 + 768 + j];

  for (int st = 0; st < TSEQ; ++st) {
    const int ttn = (st == TSEQ - 1) ? tt : tt + dt;
    u16 xn0 = xzb[(size_t)ttn * G4 + j];          // prefetch next step's xz
    u16 xn1 = xzb[(size_t)ttn * G4 + 256 + j];
    u16 xn2 = xzb[(size_t)ttn * G4 + 512 + j];
    u16 xn3 = xzb[(size_t)ttn * G4 + 768 + j];

    const int par = st & 1;
    const signed char* hb = &hpk[par][0];
    // A-frags: h replicated across rows; lane reads k = kc*64 + quad*16 .. +15
    i32x4 af0 = *(const i32x4*)(hb + q16);
    i32x4 af1 = *(const i32x4*)(hb + 64 + q16);
    i32x4 af2 = *(const i32x4*)(hb + 128 + q16);
    i32x4 af3 = *(const i32x4*)(hb + 192 + q16);

    TILE(0, 0) TILE(0, 1)    // gate i, col-subtiles 0,1
    TILE(1, 0) TILE(1, 1)    // gate f
    TILE(2, 0) TILE(2, 1)    // gate g
    TILE(3, 0) TILE(3, 1)    // gate o

    int ri = ctsel ? ac01[0] : ac00[0];
    int rf = ctsel ? ac11[0] : ac10[0];
    int rg = ctsel ? ac21[0] : ac20[0];
    int ro = ctsel ? ac31[0] : ac30[0];

    float zi = (float)ri * DEQ + f16f(x0);
    float zf = (float)rf * DEQ + f16f(x1);
    float zg = (float)rg * DEQ + f16f(x2);
    float zo = (float)ro * DEQ + f16f(x3);
    float ig = sigm_fast(zi);
    float fg = sigm_fast(zf);
    float gg = tanh_fast(zg);
    float og = sigm_fast(zo);
    float cn = fg * c + ig * gg;
    float hn = og * tanh_fast(cn);
    if (tt < len) { c = cn; h = hn; }            // masked step: hold state
    if (wr) {
      u32 hb2 = packf16(h, h);
      hrow[(size_t)tt * 512 + j] = (u16)(hb2 & 0xffffu);
      int hq = (int)__builtin_rintf(h * 127.f);
      hpk[par ^ 1][j] = (signed char)hq;
    }
    __syncthreads();
    x0 = xn0; x1 = xn1; x2 = xn2; x3 = xn3; tt = ttn;
  }
}

// ---------------- K3: logits = hcat @ dense_W + dense_b ----------------
__global__ __launch_bounds__(256) void dense_k(
    const u16* __restrict__ hcat, const float* __restrict__ W,
    const float* __restrict__ bias, float* __restrict__ out)
{
  const int lane = threadIdx.x & 63;
  const int wv = threadIdx.x >> 6;
  const int rowbase = (blockIdx.x * 4 + wv) * 8;
  for (int rr = 0; rr < 8; ++rr) {
    const int row = rowbase + rr;
    const u16* __restrict__ hr = hcat + (size_t)row * 512;
    float hv[8];
#pragma unroll
    for (int i = 0; i < 8; ++i)
      hv[i] = f16f(hr[i * 64 + lane]);
    float myout = 0.f;
#pragma unroll
    for (int cc = 0; cc < 9; ++cc) {
      float p = 0.f;
#pragma unroll
      for (int i = 0; i < 8; ++i)
        p = fmaf(hv[i], W[(size_t)(i * 64 + lane) * 9 + cc], p);
#pragma unroll
      for (int o = 32; o > 0; o >>= 1) p += __shfl_xor(p, o);
      if (lane == cc) myout = p + bias[cc];
    }
    if (lane < 9) out[(size_t)row * 9 + lane] = myout;
  }
}

// ---------------- K4: CRF log-likelihood + trans copy ----------------
__global__ __launch_bounds__(64) void crf_k(
    const float* __restrict__ logits, const int* __restrict__ tags,
    const int* __restrict__ lengths, const float* __restrict__ trans,
    float* __restrict__ out_ll, float* __restrict__ out_trans)
{
  const int b = blockIdx.x;
  const int lane = threadIdx.x;
  const int len = lengths[b];
  const float* __restrict__ lg = logits + (size_t)b * TSEQ * NCLS;
  const int* __restrict__ tg = tags + (size_t)b * TSEQ;

  float ua = 0.f, ba = 0.f;
  for (int t = lane; t < TSEQ; t += 64) {
    int tag = tg[t];
    if (t < len) ua += lg[t * 9 + tag];
    if (t < len - 1) ba += trans[tag * 9 + tg[t + 1]];
  }
  float s = ua + ba;
#pragma unroll
  for (int o = 32; o > 0; o >>= 1) s += __shfl_xor(s, o);

  const int j = (lane < 9) ? lane : 0;
  float trc[9], alpha[9];
#pragma unroll
  for (int i = 0; i < 9; ++i) trc[i] = trans[i * 9 + j];
#pragma unroll
  for (int i = 0; i < 9; ++i) alpha[i] = lg[i];
  for (int t = 1; t < TSEQ; ++t) {
    if (t >= len) break;                 // mask is monotone
    float m = -1e30f;
#pragma unroll
    for (int i = 0; i < 9; ++i) m = fmaxf(m, alpha[i] + trc[i]);
    float ss = 0.f;
#pragma unroll
    for (int i = 0; i < 9; ++i) ss += __expf(alpha[i] + trc[i] - m);
    float nj = __logf(ss) + m + lg[t * 9 + j];
#pragma unroll
    for (int i = 0; i < 9; ++i) alpha[i] = __shfl(nj, i);
  }
  float m2 = -1e30f;
#pragma unroll
  for (int i = 0; i < 9; ++i) m2 = fmaxf(m2, alpha[i]);
  float s2 = 0.f;
#pragma unroll
  for (int i = 0; i < 9; ++i) s2 += __expf(alpha[i] - m2);
  float lse = __logf(s2) + m2;
  if (lane == 0) out_ll[b] = s - lse;
  if (b == 0)
    for (int i = lane; i < 81; i += 64) out_trans[i] = trans[i];
}

// ---------------- launch ----------------
extern "C" void kernel_launch(void* const* d_in, const int* in_sizes, int n_in,
                              void* d_out, int out_size, void* d_ws, size_t ws_size,
                              hipStream_t stream)
{
  const int*   inputs  = (const int*)d_in[0];
  const int*   lengths = (const int*)d_in[1];
  const int*   targets = (const int*)d_in[2];
  const float* emb     = (const float*)d_in[3];
  const float* Wk_f    = (const float*)d_in[4];
  const float* Wr_f    = (const float*)d_in[5];
  const float* b_f     = (const float*)d_in[6];
  const float* Wk_b    = (const float*)d_in[7];
  const float* Wr_b    = (const float*)d_in[8];
  const float* b_b     = (const float*)d_in[9];
  const float* dense_W = (const float*)d_in[10];
  const float* dense_b = (const float*)d_in[11];
  const float* trans   = (const float*)d_in[12];

  char* ws = (char*)d_ws;
  u16*         wkt    = (u16*)ws;                              //  1,310,720 B
  signed char* wr8    = (signed char*)(ws + 1310720ull);       //    524,288 B
  u16*         embf16 = (u16*)(ws + 1835008ull);               // 19,200,000 B
  u16*         xz     = (u16*)(ws + 1835008ull + 19200000ull); // 134,217,728 B
  u16*         hcat   = (u16*)(ws + 1835008ull + 19200000ull + 134217728ull); // 33,554,432 B

  float* out_logits = (float*)d_out;
  float* out_ll     = out_logits + (size_t)BATCH * TSEQ * NCLS;
  float* out_trans  = out_ll + BATCH;

  hipLaunchKernelGGL(embcvt_k, dim3(1875), dim3(256), 0, stream, emb, embf16);
  hipLaunchKernelGGL(wkt_k, dim3(64, 2), dim3(256), 0, stream, Wk_f, Wk_b, wkt);
  hipLaunchKernelGGL(wr8_k, dim3(64, 2), dim3(256), 0, stream, Wr_f, Wr_b, wr8);
  hipLaunchKernelGGL(xz_gemm_k, dim3(16, 256), dim3(256), 0, stream,
                     inputs, wkt, embf16, b_f, b_b, xz);
  hipLaunchKernelGGL(lstm_k, dim3(128), dim3(512), 0, stream,
                     xz, wr8, lengths, hcat);
  hipLaunchKernelGGL(dense_k, dim3(1024), dim3(256), 0, stream,
                     hcat, dense_W, dense_b, out_logits);
  hipLaunchKernelGGL(crf_k, dim3(64), dim3(64), 0, stream,
                     out_logits, targets, lengths, trans, out_ll, out_trans);
}